// Round 1
// baseline (105.953 us; speedup 1.0000x reference)
//
#include <hip/hip_runtime.h>
#include <math.h>

// DAS beamforming: out[b][c][p] = sum_s data[b][c][s][t(s,p)]
// Table chain: ONLY the f64-emulated chain is proven bit-exact (r5/r6/r8
// absmax 0.0). r7's native-f32 version regressed (3.56). DO NOT change it.
// r8/r9: gather time invariant to occupancy -> per-CU VMEM throughput bound.
// r10: 8ch packed bf16 in one 16B slot -> 2 VMEM/sensor. absmax 0.25.
// r11 (this round): kill the per-sensor VMEM gathers entirely.
//   Per (16x16 block, sensor) the delay t spans <= 55 ticks (15*sqrt(2)px *
//   2.58 ticks/px), and delay_entry is a composition of monotone CR steps,
//   so tmin = delay_entry(axmin, aymin) is an exact lower bound with
//   t - tmin in [0,55] -> stage a 64-entry d2b window per sensor in LDS
//   (coalesced), plus the 16x24 table patch. Inner loop becomes pure LDS:
//   1 ds_read_u16 + 1 ds_read_b128 per sensor. VMEM/thread 256 -> ~56.
//   Bit-identical accumulation (same values, same s-ascending order).

#define NXY 512
#define S_CNT 128
#define T_CNT 2048
#define CH 8                       // B*2 = 4*2
#define CH_STRIDE (S_CNT * T_CNT)  // 262144 floats between channels (orig layout)
#define NPIX (NXY * NXY)
#define TAB_BYTES (NPIX * 2)       // 512 KB u16 table
#define CHUNK 32                   // sensors staged per LDS pass
#define NCHUNK (S_CNT / CHUNK)
#define WIN 64                     // d2b window entries per sensor (span <= 56)
#define PATW 24                    // staged table patch width (u16); covers 16 after &~7 align

#pragma float_control(push)
#pragma float_control(precise, on)
__device__ __forceinline__ unsigned short delay_entry(int adx, int ady) {
    const double DX32 = (double)1e-4f;                        // f32 const, exact widen
    const double R1 = (double)(float)(1.0 / 1550.0);          // CR f32 reciprocal
    const double R2 = (double)(float)(1.0 / (double)2.5e-8f); // = 4.0e7 exactly
    float dxf = (float)((double)adx * DX32);        // exact f64 product -> f32 round
    float dyf = (float)((double)ady * DX32);
    float a2 = (float)((double)dxf * (double)dxf);  // exact in f64 -> f32 round
    float b2 = (float)((double)dyf * (double)dyf);
    float sum = (float)((double)a2 + (double)b2);   // exact in f64 -> f32 round
    float dis = (float)sqrt((double)sum);           // CR f32 sqrt
    float q1 = (float)((double)dis * R1);           // CR f32 mul
    float q2 = (float)((double)q1 * R2);            // CR f32 mul
    return (unsigned short)(int)q2;                 // trunc; max 1864
}

__device__ __forceinline__ unsigned int bf16_rne(float f) {
    unsigned int x = __float_as_uint(f);
    return (x + 0x7fffu + ((x >> 16) & 1u)) >> 16;  // round-to-nearest-even
}

// Fused: table entry idx + transpose-convert (8ch,128s,2048t)f32 ->
// (128s,2048t)x(8ch bf16 packed in 16B).
__global__ __launch_bounds__(256) void prep(const float* __restrict__ data,
                                            unsigned short* __restrict__ tab,
                                            uint4* __restrict__ d2b) {
    int idx = blockIdx.x * 256 + threadIdx.x;  // 0 .. 262143 (NPIX == 128*2048)
    tab[idx] = delay_entry(idx >> 9, idx & 511);

    unsigned int w[4];
#pragma unroll
    for (int j = 0; j < 4; ++j) {
        unsigned int lo = bf16_rne(data[(2 * j) * CH_STRIDE + idx]);
        unsigned int hi = bf16_rne(data[(2 * j + 1) * CH_STRIDE + idx]);
        w[j] = lo | (hi << 16);
    }
    d2b[idx] = make_uint4(w[0], w[1], w[2], w[3]);
}

// meta helper must carry precise semantics (defined under the pragma, like prep's use)
__device__ __forceinline__ int tmin_entry(int adx, int ady) {
    return (int)delay_entry(adx, ady);
}
#pragma float_control(pop)

__device__ __forceinline__ float bflo(unsigned int u) { return __uint_as_float(u << 16); }
__device__ __forceinline__ float bfhi(unsigned int u) { return __uint_as_float(u & 0xffff0000u); }

// Gather v2: LDS-staged windows. 1 thread = 1 pixel x 8 channels.
// Wave = 8x8 pixel tile, block = 16x16 px (4 waves). 58 KB LDS -> 2 blocks/CU.
__global__ __launch_bounds__(256) void das_gather_lds(const uint4* __restrict__ d2b,
                                                      const unsigned short* __restrict__ tab,
                                                      const int* __restrict__ sxy,
                                                      float* __restrict__ out) {
    __shared__ int4 meta[S_CNT];              // sx, sy, ax0 | ay0<<16, tmin   (2 KB)
    __shared__ uint4 winb[CHUNK * WIN];       // d2b windows, 32 KB
    __shared__ uint4 patb[CHUNK * 16 * 3];    // table patches 16 rows x 48 B, 24 KB
    const unsigned short* pat16 = (const unsigned short*)patb;

    int tid = threadIdx.x;
    int x0 = (blockIdx.x >> 5) << 4;  // tile origin
    int y0 = (blockIdx.x & 31) << 4;

    if (tid < S_CNT) {
        int sxv = sxy[2 * tid];
        int syv = sxy[2 * tid + 1];
        // component-wise min/max of |sx-ix|, |sy-iy| over the 16x16 tile
        int axm = sxv < x0 ? x0 - sxv : (sxv > x0 + 15 ? sxv - x0 - 15 : 0);
        int aym = syv < y0 ? y0 - syv : (syv > y0 + 15 ? syv - y0 - 15 : 0);
        int ay0 = aym & ~7;                     // 16B-align patch column start
        int tmin = tmin_entry(axm, aym);        // exact monotone lower bound
        meta[tid] = make_int4(sxv, syv, axm | (ay0 << 16), tmin);
    }
    __syncthreads();

    // lane bits: iy[2:0]=tid[2:0], ix[2:0]=tid[5:3]; wave bits: iy[3]=tid[6], ix[3]=tid[7]
    int iy = y0 | (((tid >> 6) & 1) << 3) | (tid & 7);
    int ix = x0 | ((tid >> 7) << 3) | ((tid >> 3) & 7);

    float acc[CH];
#pragma unroll
    for (int k = 0; k < CH; ++k) acc[k] = 0.0f;

    for (int c = 0; c < NCHUNK; ++c) {
        int s0 = c * CHUNK;

        // --- stage d2b windows: 32 sensors x 64 x 16B = 32 KB, 8 uint4/thread.
        // 8 consecutive lanes load 128B contiguous of one sensor's window.
        {
            int lsw = tid >> 3;  // local sensor 0..31
            int tm = meta[s0 + lsw].w;
            const uint4* src = d2b + ((s0 + lsw) << 11) + tm;
            int e0 = tid & 7;
#pragma unroll
            for (int j = 0; j < 8; ++j)
                winb[(lsw << 6) + e0 + 8 * j] = src[e0 + 8 * j];
        }

        // --- stage table patches: 32 sensors x 16 rows x 3 uint4 = 24 KB, 6/thread.
        // row byte base = (ax0+row)*1024 + ay0*2 (+c*16); ay0 even-8 -> 16B aligned.
        // Worst case reads 16B past the table end (into d2b base) - staged but unused.
#pragma unroll
        for (int j = 0; j < 6; ++j) {
            unsigned int idx = (unsigned int)tid + 256u * j;  // 0..1535
            unsigned int r3 = idx / 3u;                       // 0..511 (magic mul)
            unsigned int cc = idx - r3 * 3u;                  // 0..2
            unsigned int row = r3 & 15u;
            unsigned int ls = r3 >> 4;                        // 0..31
            int4 m = meta[s0 + ls];
            int ax0 = m.z & 0xffff;
            int ay0 = m.z >> 16;
            const uint4* src = (const uint4*)((const char*)tab +
                (((size_t)(ax0 + (int)row) << 10) + ((size_t)ay0 << 1) + ((size_t)cc << 4)));
            patb[ls * 48u + row * 3u + cc] = *src;
        }
        __syncthreads();

        // --- pure-LDS inner loop: 1 ds_read_u16 + 1 ds_read_b128 per sensor
#pragma unroll 4
        for (int ls = 0; ls < CHUNK; ++ls) {
            int4 m = meta[s0 + ls];  // broadcast b128
            int dxi = m.x - ix;
            int dyi = m.y - iy;
            int adx = dxi < 0 ? -dxi : dxi;
            int ady = dyi < 0 ? -dyi : dyi;
            int ax0 = m.z & 0xffff;
            int ay0 = m.z >> 16;
            int t = (int)pat16[ls * (16 * PATW) + (adx - ax0) * PATW + (ady - ay0)];
            uint4 w = winb[(ls << 6) + (t - m.w)];  // t - tmin in [0,55]
            acc[0] += bflo(w.x);  // per-channel s-ascending: deterministic
            acc[1] += bfhi(w.x);
            acc[2] += bflo(w.y);
            acc[3] += bfhi(w.y);
            acc[4] += bflo(w.z);
            acc[5] += bfhi(w.z);
            acc[6] += bflo(w.w);
            acc[7] += bfhi(w.w);
        }
        __syncthreads();  // protect LDS before next chunk's staging
    }

    int pix = (ix << 9) | iy;
#pragma unroll
    for (int k = 0; k < CH; ++k) out[k * NPIX + pix] = acc[k];
}

// ---------- fallback path (ws too small): r5-proven build_table + das_main ----------
#pragma float_control(push)
#pragma float_control(precise, on)
__global__ __launch_bounds__(256) void build_table(unsigned short* __restrict__ tab) {
    int idx = blockIdx.x * 256 + threadIdx.x;
    tab[idx] = delay_entry(idx >> 9, idx & 511);
}
#pragma float_control(pop)

__global__ __launch_bounds__(256) void das_main(const float* __restrict__ data,
                                                const unsigned short* __restrict__ tab,
                                                const int* __restrict__ sxy,
                                                float* __restrict__ out) {
    __shared__ int sx[S_CNT];
    __shared__ int sy[S_CNT];
    int tid = threadIdx.x;
    if (tid < S_CNT) {
        sx[tid] = sxy[2 * tid];
        sy[tid] = sxy[2 * tid + 1];
    }
    __syncthreads();
    int iy = ((blockIdx.x & 31) << 4) | (tid & 15);
    int ix = ((blockIdx.x >> 5) << 4) | (tid >> 4);
    float acc[CH];
#pragma unroll
    for (int k = 0; k < CH; ++k) acc[k] = 0.0f;
#pragma unroll 4
    for (int s = 0; s < S_CNT; ++s) {
        int dxi = sx[s] - ix;
        int dyi = sy[s] - iy;
        int adx = dxi < 0 ? -dxi : dxi;
        int ady = dyi < 0 ? -dyi : dyi;
        int t = (int)tab[(adx << 9) | ady];
        const float* p = data + (s << 11) + t;
#pragma unroll
        for (int k = 0; k < CH; ++k) acc[k] += p[(size_t)k * CH_STRIDE];
    }
    int pix = (ix << 9) | iy;
#pragma unroll
    for (int k = 0; k < CH; ++k) out[k * NPIX + pix] = acc[k];
}

extern "C" void kernel_launch(void* const* d_in, const int* in_sizes, int n_in,
                              void* d_out, int out_size, void* d_ws, size_t ws_size,
                              hipStream_t stream) {
    const float* data = (const float*)d_in[0];     // (4,2,128,2048) f32
    const int* sxy = (const int*)d_in[1];          // (128,2) i32
    float* out = (float*)d_out;                    // (4,2,512,512) f32
    unsigned short* tab = (unsigned short*)d_ws;   // 512 KB

    size_t need = (size_t)TAB_BYTES + (size_t)CH_STRIDE * 16;  // 512KB + 4MB
    if (ws_size >= need) {
        uint4* d2b = (uint4*)((char*)d_ws + TAB_BYTES);
        prep<<<NPIX / 256, 256, 0, stream>>>(data, tab, d2b);
        das_gather_lds<<<1024, 256, 0, stream>>>(d2b, tab, sxy, out);
    } else {
        build_table<<<NPIX / 256, 256, 0, stream>>>(tab);
        das_main<<<1024, 256, 0, stream>>>(data, tab, sxy, out);
    }
}